// Round 14
// baseline (92.620 us; speedup 1.0000x reference)
//
#include <hip/hip_runtime.h>

// Problem constants (match reference)
#define N_ 2048
#define D_ 16
#define O_ 3
#define S_ 10
#define E_ 4096
#define K_ 128

constexpr float STEP = 0.1f;            // (T_LAST - T_INIT) / S
constexpr int TILE = 128;
constexpr int T_ = N_ / TILE;           // 16 tile rows
constexpr int TP_ = T_ * (T_ + 1) / 2;  // 136 triangular tile pairs
constexpr int PAIR_BLOCKS = S_ * TP_;   // 1360
constexpr int EVENT_BLOCKS = E_ / 8;    // 512 (8 events per block, 1 per wave)
constexpr int GRID = PAIR_BLOCKS + EVENT_BLOCKS; // 1872
constexpr float LOG2E = 1.4426950408889634f;

// d_ws layout (floats unless noted):
//   X  [S_][N_][D_]  : 327680 floats
//   SQ [S_][N_]      : 20480 floats
//   GL [N_]          : 2048 floats
//   slots [GRID] dbl : at byte offset 1,400,832 (8B aligned)
constexpr size_t XF_   = 0;
constexpr size_t SQF_  = 327680;
constexpr size_t GLF_  = SQF_ + 20480;
constexpr size_t SLOTB = (GLF_ + 2048) * 4;

struct PairSm {
    // row stride = 9 float2 = 72 B: 8B-aligned ds_read_b64; with chunk
    // rotation ce=(cc+(tc>>1))&7 reads are <=2-way (validated R7: 0.70M
    // conflict cycles ~= free).
    float2 xR[TILE][9];
    float2 xC[TILE][9];
    float sqR[TILE];
    float sqC[TILE];
    float gR[TILE];   // gamma * LOG2E
    float gC[TILE];
};
struct EvSm {
    float dz[8][O_][D_];   // eight events per block (one per wave)
};

// ---- precompute: X(s,n,:) = z0_0 + t z0_1 + t^2/2 z0_2 ; SQ = |X|^2 ;
// ---- GL = gamma*LOG2E.  20480 row-threads (80 blocks x 256).
__global__ __launch_bounds__(256) void nhpp_pre(
    const float* __restrict__ gamma,
    const float* __restrict__ z0,
    float* __restrict__ X,
    float* __restrict__ SQ,
    float* __restrict__ GL)
{
    const int g = blockIdx.x * 256 + threadIdx.x;   // 0..20479
    const int s = g >> 11;
    const int n = g & (N_ - 1);
    const float t  = STEP * (float)s;
    const float c1 = t;
    const float c2 = 0.5f * t * t;

    const float2* p0 = (const float2*)(z0 + (0 * N_ + n) * D_);
    const float2* p1 = (const float2*)(z0 + (1 * N_ + n) * D_);
    const float2* p2 = (const float2*)(z0 + (2 * N_ + n) * D_);
    float2* xo = (float2*)(X + ((size_t)s * N_ + n) * D_);

    float ssq = 0.f;
    #pragma unroll
    for (int ch = 0; ch < 8; ++ch) {
        const float2 a = p0[ch], b = p1[ch], c = p2[ch];
        float2 x;
        x.x = fmaf(c2, c.x, fmaf(c1, b.x, a.x));
        x.y = fmaf(c2, c.y, fmaf(c1, b.y, a.y));
        ssq = fmaf(x.x, x.x, fmaf(x.y, x.y, ssq));
        xo[ch] = x;
    }
    SQ[s * N_ + n] = ssq;
    if (g < N_) GL[g] = gamma[g] * LOG2E;
}

// ---- main: pair tiles read precomputed X/SQ/GL (copy-only staging, one
// ---- barrier). Micro-kernel = R11's 4x8 (best measured). 512 threads.
__global__ __launch_bounds__(512) void nhpp_main(
    const float* __restrict__ gamma,
    const float* __restrict__ z0,
    const float* __restrict__ et,
    const int* __restrict__ pairs,
    const float* __restrict__ X,
    const float* __restrict__ SQ,
    const float* __restrict__ GL,
    double* __restrict__ slots)      // [GRID], one per block, no atomics
{
    __shared__ union { PairSm p; EvSm ev; } sm;
    __shared__ float wred[8];

    const int tid = threadIdx.x;
    const int bid = blockIdx.x;

    if (bid < PAIR_BLOCKS) {
        // ---------------- pairwise integral path ----------------
        const int s = bid / TP_;
        int rem = bid % TP_;
        int ti = 0;
        while (rem >= T_ - ti) { rem -= T_ - ti; ++ti; }
        const int tj = ti + rem;
        const bool diag = (ti == tj);

        // stage X tiles (pure copy, fully coalesced) + SQ/GL rows.
        const float2* Xs = (const float2*)(X + (size_t)s * N_ * D_);
        #pragma unroll
        for (int it = 0; it < 4; ++it) {
            const int e4 = it * 512 + tid;
            const int r  = (e4 >> 3) & 127;
            const int ch = e4 & 7;
            const int n  = ((it < 2) ? ti : tj) * TILE + r;
            const float2 v = Xs[n * 8 + ch];
            if (it < 2) sm.p.xR[r][ch] = v;
            else        sm.p.xC[r][ch] = v;
        }
        if (tid < 256) {
            const int r = tid & 127;
            const int n = ((tid < 128) ? ti : tj) * TILE + r;
            const float sq = SQ[s * N_ + n];
            const float gl = GL[n];
            if (tid < 128) { sm.p.sqR[r] = sq; sm.p.gR[r] = gl; }
            else           { sm.p.sqC[r] = sq; sm.p.gC[r] = gl; }
        }
        __syncthreads();

        // 4x8 register micro-tile over a 128x128 tile (32 x 16 threads).
        const int tr = tid >> 4;    // 0..31
        const int tc = tid & 15;    // 0..15
        const int r0 = tr * 4, c0 = tc * 8;
        const int rot = (tc >> 1) & 7;

        float a8[4][8];
        #pragma unroll
        for (int i = 0; i < 4; ++i)
            #pragma unroll
            for (int j = 0; j < 8; ++j) a8[i][j] = 0.f;

        #pragma unroll
        for (int cc = 0; cc < 8; ++cc) {
            const int ce = (cc + rot) & 7;
            float2 xr[4], xc[8];
            #pragma unroll
            for (int i = 0; i < 4; ++i) xr[i] = sm.p.xR[r0 + i][ce];
            #pragma unroll
            for (int j = 0; j < 8; ++j) xc[j] = sm.p.xC[c0 + j][ce];
            #pragma unroll
            for (int i = 0; i < 4; ++i)
                #pragma unroll
                for (int j = 0; j < 8; ++j)
                    a8[i][j] = fmaf(xr[i].x, xc[j].x,
                               fmaf(xr[i].y, xc[j].y, a8[i][j]));
        }

        float sqr[4], grl[4];
        #pragma unroll
        for (int i = 0; i < 4; ++i) {
            sqr[i] = sm.p.sqR[r0 + i];
            grl[i] = sm.p.gR[r0 + i];
        }

        float ls0 = 0.f, ls1 = 0.f;
        #pragma unroll
        for (int j = 0; j < 8; ++j) {
            const float sqc = sm.p.sqC[c0 + j];
            const float gcl = sm.p.gC[c0 + j];
            #pragma unroll
            for (int i = 0; i < 4; ++i) {
                const float d2   = fmaf(-2.0f, a8[i][j], sqr[i] + sqc);
                const float dist = sqrtf(fmaxf(d2, 0.0f));
                float v = exp2f(fmaf(-LOG2E, dist, grl[i] + gcl));
                if (diag) v = (r0 + i < c0 + j) ? v : 0.f;
                if (i & 1) ls1 += v; else ls0 += v;
            }
        }
        float lsum = ls0 + ls1;

        #pragma unroll
        for (int off = 32; off; off >>= 1) lsum += __shfl_down(lsum, off, 64);
        if ((tid & 63) == 0) wred[tid >> 6] = lsum;
        __syncthreads();
        if (tid == 0) {
            float b = 0.f;
            #pragma unroll
            for (int k = 0; k < 8; ++k) b += wred[k];
            slots[bid] = (double)(b * STEP);
        }
    } else {
        // ---------------- event log-intensity path ----------------
        const int bb   = bid - PAIR_BLOCKS;
        const int w    = tid >> 6;       // wave = event slot (0..7)
        const int lane = tid & 63;
        const int e    = bb * 8 + w;
        const int pi   = pairs[2 * e + 0];
        const int pj   = pairs[2 * e + 1];

        if (lane < O_ * D_) {
            const int o = lane >> 4, d = lane & 15;
            const float inv = (o == 2) ? 0.5f : 1.0f;   // 1/fact
            sm.ev.dz[w][o][d] =
                (z0[(o * N_ + pi) * D_ + d] - z0[(o * N_ + pj) * D_ + d]) * inv;
        }
        __syncthreads();

        const float2 tt = *(const float2*)(et + e * K_ + 2 * lane);
        float ed = 0.f;
        #pragma unroll
        for (int h = 0; h < 2; ++h) {
            const float tk = (h == 0) ? tt.x : tt.y;
            float ss = 0.f;
            #pragma unroll
            for (int d = 0; d < D_; ++d) {
                const float v = fmaf(tk, fmaf(tk, sm.ev.dz[w][2][d],
                                              sm.ev.dz[w][1][d]),
                                     sm.ev.dz[w][0][d]);
                ss = fmaf(v, v, ss);
            }
            ed += sqrtf(fmaxf(ss, 0.0f));
        }
        #pragma unroll
        for (int off = 32; off; off >>= 1) ed += __shfl_down(ed, off, 64);
        if (lane == 0)
            wred[w] = ed - (float)K_ * (gamma[pi] + gamma[pj]); // = -log_int
        __syncthreads();
        if (tid == 0) {
            float b = 0.f;
            #pragma unroll
            for (int k = 0; k < 8; ++k) b += wred[k];
            slots[bid] = (double)b;
        }
    }
}

// Final reduction over per-block partials — separate dispatch; every slot
// is written unconditionally by its block (harness poison always overwritten).
__global__ __launch_bounds__(512) void nhpp_reduce(
    const double* __restrict__ slots, float* __restrict__ out)
{
    __shared__ double w8[8];
    const int tid = threadIdx.x;
    double s = 0.0;
    for (int i = tid; i < GRID; i += 512) s += slots[i];
    #pragma unroll
    for (int off = 32; off; off >>= 1) s += __shfl_down(s, off, 64);
    if ((tid & 63) == 0) w8[tid >> 6] = s;
    __syncthreads();
    if (tid == 0) {
        double t = 0.0;
        #pragma unroll
        for (int k = 0; k < 8; ++k) t += w8[k];
        out[0] = (float)t;
    }
}

extern "C" void kernel_launch(void* const* d_in, const int* in_sizes, int n_in,
                              void* d_out, int out_size, void* d_ws, size_t ws_size,
                              hipStream_t stream) {
    (void)in_sizes; (void)n_in; (void)out_size; (void)ws_size;
    const float* gamma = (const float*)d_in[0];
    const float* z0    = (const float*)d_in[1];
    const float* et    = (const float*)d_in[2];
    const int*   pairs = (const int*)d_in[3];
    float* out = (float*)d_out;

    float*  X     = (float*)d_ws + XF_;
    float*  SQ    = (float*)d_ws + SQF_;
    float*  GL    = (float*)d_ws + GLF_;
    double* slots = (double*)((char*)d_ws + SLOTB);

    nhpp_pre<<<80, 256, 0, stream>>>(gamma, z0, X, SQ, GL);
    nhpp_main<<<GRID, 512, 0, stream>>>(gamma, z0, et, pairs, X, SQ, GL, slots);
    nhpp_reduce<<<1, 512, 0, stream>>>(slots, out);
}

// Round 15
// 91.177 us; speedup vs baseline: 1.0158x; 1.0158x over previous
//
#include <hip/hip_runtime.h>

// Problem constants (match reference)
#define N_ 2048
#define D_ 16
#define O_ 3
#define S_ 10
#define E_ 4096
#define K_ 128

constexpr float STEP = 0.1f;            // (T_LAST - T_INIT) / S
constexpr int TILE = 128;
constexpr int T_ = N_ / TILE;           // 16 tile rows
constexpr int TP_ = T_ * (T_ + 1) / 2;  // 136 triangular tile pairs
constexpr int PAIR_BLOCKS = S_ * TP_;   // 1360
constexpr int EVENT_BLOCKS = E_ / 8;    // 512 (8 events per block, 1 per wave)
constexpr int GRID = PAIR_BLOCKS + EVENT_BLOCKS; // 1872
constexpr float LOG2E = 1.4426950408889634f;

// d_ws layout (floats unless noted):
//   X  [S_][N_][D_]  : 327680 floats
//   SQ [S_][N_]      : 20480 floats
//   GL [N_]          : 2048 floats
//   slots [GRID] dbl : at byte offset 1,400,832 (8B aligned)
constexpr size_t XF_   = 0;
constexpr size_t SQF_  = 327680;
constexpr size_t GLF_  = SQF_ + 20480;
constexpr size_t SLOTB = (GLF_ + 2048) * 4;

struct PairSm {
    // row stride = 9 float2 = 72 B: 8B-aligned ds_read_b64; with chunk
    // rotation ce=(cc+(tc>>1))&7 reads are <=2-way (validated R7: 0.70M
    // conflict cycles ~= free).
    float2 xR[TILE][9];
    float2 xC[TILE][9];
    float sqR[TILE];
    float sqC[TILE];
    float gR[TILE];   // gamma * LOG2E
    float gC[TILE];
};
struct EvSm {
    float dz[8][O_][D_];   // eight events per block (one per wave)
};

// ---- precompute: X(s,n,:) = z0_0 + t z0_1 + t^2/2 z0_2 ; SQ = |X|^2 ;
// ---- GL = gamma*LOG2E.  20480 row-threads (80 blocks x 256).
__global__ __launch_bounds__(256) void nhpp_pre(
    const float* __restrict__ gamma,
    const float* __restrict__ z0,
    float* __restrict__ X,
    float* __restrict__ SQ,
    float* __restrict__ GL)
{
    const int g = blockIdx.x * 256 + threadIdx.x;   // 0..20479
    const int s = g >> 11;
    const int n = g & (N_ - 1);
    const float t  = STEP * (float)s;
    const float c1 = t;
    const float c2 = 0.5f * t * t;

    const float2* p0 = (const float2*)(z0 + (0 * N_ + n) * D_);
    const float2* p1 = (const float2*)(z0 + (1 * N_ + n) * D_);
    const float2* p2 = (const float2*)(z0 + (2 * N_ + n) * D_);
    float2* xo = (float2*)(X + ((size_t)s * N_ + n) * D_);

    float ssq = 0.f;
    #pragma unroll
    for (int ch = 0; ch < 8; ++ch) {
        const float2 a = p0[ch], b = p1[ch], c = p2[ch];
        float2 x;
        x.x = fmaf(c2, c.x, fmaf(c1, b.x, a.x));
        x.y = fmaf(c2, c.y, fmaf(c1, b.y, a.y));
        ssq = fmaf(x.x, x.x, fmaf(x.y, x.y, ssq));
        xo[ch] = x;
    }
    SQ[s * N_ + n] = ssq;
    if (g < N_) GL[g] = gamma[g] * LOG2E;
}

// ---- main: pair tiles read precomputed X/SQ/GL (copy-only staging, one
// ---- barrier). 4x8 micro-tile; accumulators pinned to arch VGPRs via
// ---- inline-asm v_fmac_f32 ("+v") — R7/R14 showed LLVM otherwise parks
// ---- them in AGPRs (VGPR_Count=36!) with accvgpr_read/write around
// ---- every FMA (~3-4x inner-loop VALU inflation).
__global__ __launch_bounds__(512) void nhpp_main(
    const float* __restrict__ gamma,
    const float* __restrict__ z0,
    const float* __restrict__ et,
    const int* __restrict__ pairs,
    const float* __restrict__ X,
    const float* __restrict__ SQ,
    const float* __restrict__ GL,
    double* __restrict__ slots)      // [GRID], one per block, no atomics
{
    __shared__ union { PairSm p; EvSm ev; } sm;
    __shared__ float wred[8];

    const int tid = threadIdx.x;
    const int bid = blockIdx.x;

    if (bid < PAIR_BLOCKS) {
        // ---------------- pairwise integral path ----------------
        const int s = bid / TP_;
        int rem = bid % TP_;
        int ti = 0;
        while (rem >= T_ - ti) { rem -= T_ - ti; ++ti; }
        const int tj = ti + rem;
        const bool diag = (ti == tj);

        // stage X tiles (pure copy, fully coalesced) + SQ/GL rows.
        const float2* Xs = (const float2*)(X + (size_t)s * N_ * D_);
        #pragma unroll
        for (int it = 0; it < 4; ++it) {
            const int e4 = it * 512 + tid;
            const int r  = (e4 >> 3) & 127;
            const int ch = e4 & 7;
            const int n  = ((it < 2) ? ti : tj) * TILE + r;
            const float2 v = Xs[n * 8 + ch];
            if (it < 2) sm.p.xR[r][ch] = v;
            else        sm.p.xC[r][ch] = v;
        }
        if (tid < 256) {
            const int r = tid & 127;
            const int n = ((tid < 128) ? ti : tj) * TILE + r;
            const float sq = SQ[s * N_ + n];
            const float gl = GL[n];
            if (tid < 128) { sm.p.sqR[r] = sq; sm.p.gR[r] = gl; }
            else           { sm.p.sqC[r] = sq; sm.p.gC[r] = gl; }
        }
        __syncthreads();

        // 4x8 register micro-tile over a 128x128 tile (32 x 16 threads).
        const int tr = tid >> 4;    // 0..31
        const int tc = tid & 15;    // 0..15
        const int r0 = tr * 4, c0 = tc * 8;
        const int rot = (tc >> 1) & 7;

        float a8[4][8];
        #pragma unroll
        for (int i = 0; i < 4; ++i)
            #pragma unroll
            for (int j = 0; j < 8; ++j) a8[i][j] = 0.f;

        #pragma unroll
        for (int cc = 0; cc < 8; ++cc) {
            const int ce = (cc + rot) & 7;
            float2 xr[4], xc[8];
            #pragma unroll
            for (int i = 0; i < 4; ++i) xr[i] = sm.p.xR[r0 + i][ce];
            #pragma unroll
            for (int j = 0; j < 8; ++j) xc[j] = sm.p.xC[c0 + j][ce];
            #pragma unroll
            for (int i = 0; i < 4; ++i)
                #pragma unroll
                for (int j = 0; j < 8; ++j) {
                    // acc += xr.x*xc.x; acc += xr.y*xc.y — pinned to VGPRs.
                    asm("v_fmac_f32 %0, %1, %2"
                        : "+v"(a8[i][j]) : "v"(xr[i].x), "v"(xc[j].x));
                    asm("v_fmac_f32 %0, %1, %2"
                        : "+v"(a8[i][j]) : "v"(xr[i].y), "v"(xc[j].y));
                }
        }

        float sqr[4], grl[4];
        #pragma unroll
        for (int i = 0; i < 4; ++i) {
            sqr[i] = sm.p.sqR[r0 + i];
            grl[i] = sm.p.gR[r0 + i];
        }

        float ls0 = 0.f, ls1 = 0.f;
        #pragma unroll
        for (int j = 0; j < 8; ++j) {
            const float sqc = sm.p.sqC[c0 + j];
            const float gcl = sm.p.gC[c0 + j];
            #pragma unroll
            for (int i = 0; i < 4; ++i) {
                const float d2   = fmaf(-2.0f, a8[i][j], sqr[i] + sqc);
                const float dist = sqrtf(fmaxf(d2, 0.0f));
                float v = exp2f(fmaf(-LOG2E, dist, grl[i] + gcl));
                if (diag) v = (r0 + i < c0 + j) ? v : 0.f;
                if (i & 1) ls1 += v; else ls0 += v;
            }
        }
        float lsum = ls0 + ls1;

        #pragma unroll
        for (int off = 32; off; off >>= 1) lsum += __shfl_down(lsum, off, 64);
        if ((tid & 63) == 0) wred[tid >> 6] = lsum;
        __syncthreads();
        if (tid == 0) {
            float b = 0.f;
            #pragma unroll
            for (int k = 0; k < 8; ++k) b += wred[k];
            slots[bid] = (double)(b * STEP);
        }
    } else {
        // ---------------- event log-intensity path ----------------
        const int bb   = bid - PAIR_BLOCKS;
        const int w    = tid >> 6;       // wave = event slot (0..7)
        const int lane = tid & 63;
        const int e    = bb * 8 + w;
        const int pi   = pairs[2 * e + 0];
        const int pj   = pairs[2 * e + 1];

        if (lane < O_ * D_) {
            const int o = lane >> 4, d = lane & 15;
            const float inv = (o == 2) ? 0.5f : 1.0f;   // 1/fact
            sm.ev.dz[w][o][d] =
                (z0[(o * N_ + pi) * D_ + d] - z0[(o * N_ + pj) * D_ + d]) * inv;
        }
        __syncthreads();

        const float2 tt = *(const float2*)(et + e * K_ + 2 * lane);
        float ed = 0.f;
        #pragma unroll
        for (int h = 0; h < 2; ++h) {
            const float tk = (h == 0) ? tt.x : tt.y;
            float ss = 0.f;
            #pragma unroll
            for (int d = 0; d < D_; ++d) {
                const float v = fmaf(tk, fmaf(tk, sm.ev.dz[w][2][d],
                                              sm.ev.dz[w][1][d]),
                                     sm.ev.dz[w][0][d]);
                ss = fmaf(v, v, ss);
            }
            ed += sqrtf(fmaxf(ss, 0.0f));
        }
        #pragma unroll
        for (int off = 32; off; off >>= 1) ed += __shfl_down(ed, off, 64);
        if (lane == 0)
            wred[w] = ed - (float)K_ * (gamma[pi] + gamma[pj]); // = -log_int
        __syncthreads();
        if (tid == 0) {
            float b = 0.f;
            #pragma unroll
            for (int k = 0; k < 8; ++k) b += wred[k];
            slots[bid] = (double)b;
        }
    }
}

// Final reduction over per-block partials — separate dispatch; every slot
// is written unconditionally by its block (harness poison always overwritten).
__global__ __launch_bounds__(512) void nhpp_reduce(
    const double* __restrict__ slots, float* __restrict__ out)
{
    __shared__ double w8[8];
    const int tid = threadIdx.x;
    double s = 0.0;
    for (int i = tid; i < GRID; i += 512) s += slots[i];
    #pragma unroll
    for (int off = 32; off; off >>= 1) s += __shfl_down(s, off, 64);
    if ((tid & 63) == 0) w8[tid >> 6] = s;
    __syncthreads();
    if (tid == 0) {
        double t = 0.0;
        #pragma unroll
        for (int k = 0; k < 8; ++k) t += w8[k];
        out[0] = (float)t;
    }
}

extern "C" void kernel_launch(void* const* d_in, const int* in_sizes, int n_in,
                              void* d_out, int out_size, void* d_ws, size_t ws_size,
                              hipStream_t stream) {
    (void)in_sizes; (void)n_in; (void)out_size; (void)ws_size;
    const float* gamma = (const float*)d_in[0];
    const float* z0    = (const float*)d_in[1];
    const float* et    = (const float*)d_in[2];
    const int*   pairs = (const int*)d_in[3];
    float* out = (float*)d_out;

    float*  X     = (float*)d_ws + XF_;
    float*  SQ    = (float*)d_ws + SQF_;
    float*  GL    = (float*)d_ws + GLF_;
    double* slots = (double*)((char*)d_ws + SLOTB);

    nhpp_pre<<<80, 256, 0, stream>>>(gamma, z0, X, SQ, GL);
    nhpp_main<<<GRID, 512, 0, stream>>>(gamma, z0, et, pairs, X, SQ, GL, slots);
    nhpp_reduce<<<1, 512, 0, stream>>>(slots, out);
}